// Round 1
// 788.899 us; speedup vs baseline: 1.0713x; 1.0713x over previous
//
#include <hip/hip_runtime.h>
#include <hip/hip_bf16.h>

#define Bb 8
#define Ss 512
#define Nn 128
#define DIN 256
#define DHID 128
#define DOUT 64
#define TN 16   // n rows per tile / block
#define TS 32   // s values per block (16 chunks)

typedef __attribute__((ext_vector_type(8))) __bf16 bf16x8;
typedef __attribute__((ext_vector_type(4))) __bf16 bf16x4;
typedef __attribute__((ext_vector_type(4))) float f32x4;

__device__ __forceinline__ unsigned short f2bf(float f) {
  unsigned u = __float_as_uint(f);
  u += 0x7fffu + ((u >> 16) & 1u);
  return (unsigned short)(u >> 16);
}
__device__ __forceinline__ float bf2f(unsigned short h) {
  return __uint_as_float(((unsigned)h) << 16);
}

// ---- prep: split W1 (128x256 fp32) into bf16 hi + lo residual ----
__global__ void prep_w1(const float* __restrict__ W1,
                        unsigned short* __restrict__ w1h,
                        unsigned short* __restrict__ w1l) {
  int i = blockIdx.x * 256 + threadIdx.x;   // grid 128 -> 32768 = exact
  float f = W1[i];
  unsigned short h = f2bf(f);
  w1h[i] = h;
  w1l[i] = f2bf(f - bf2f(h));
}

// Convert 4 floats -> bf16 hi (RNE, via native casts -> v_cvt_pk_bf16_f32)
// + bf16 lo residual; store as two 8B writes into an xs row.
__device__ __forceinline__ void stage4(unsigned short* row, int ci, float4 v) {
  bf16x4 hv, lv;
  hv[0] = (__bf16)v.x; hv[1] = (__bf16)v.y;
  hv[2] = (__bf16)v.z; hv[3] = (__bf16)v.w;
  lv[0] = (__bf16)(v.x - (float)hv[0]);
  lv[1] = (__bf16)(v.y - (float)hv[1]);
  lv[2] = (__bf16)(v.z - (float)hv[2]);
  lv[3] = (__bf16)(v.w - (float)hv[3]);
  *(bf16x4*)(row + ci) = hv;
  *(bf16x4*)(row + 256 + ci) = lv;
}

// ---- fused flash kernel: scores + online softmax + weighted pooling ----
// grid 1024 = b(8) x ng(8) x sc(16); block 512 = 8 waves.
// Per s-tile: stage x hi/lo bf16 in double-buffered LDS; operand-swapped
// MFMA gives C[hid, n] so wave w's 16 hid cols reduce in-lane; cross-wave
// reduce via part[]; softmax state + pooled acc held redundantly per wave
// (rows r1=w, r2=w+8), pooling directly from the raw fp32 registers each
// thread staged (no LDS round-trip). 2 barriers per s-iter.
__global__ __launch_bounds__(512, 4) void flash_kernel(
    const float* __restrict__ x, const unsigned short* __restrict__ w1h,
    const unsigned short* __restrict__ w1l, const float* __restrict__ b1,
    const float* __restrict__ wlen, const int* __restrict__ seqlen,
    float* __restrict__ pml, float* __restrict__ pp) {
  __shared__ __align__(16) unsigned short xs0[TN * 520];  // hi [0,256), lo [256,512), pad 8
  __shared__ __align__(16) unsigned short xs1[TN * 520];
  __shared__ float part[128];   // [wave][n] flat

  const int t = threadIdx.x;
  const int lane = t & 63;
  const int w = t >> 6;        // wave 0..7
  const int quad = lane >> 4;  // 0..3
  const int l15 = lane & 15;

  const int bi = blockIdx.x;
  const int b = bi >> 7;
  const int ng = (bi >> 4) & 7;
  const int sc = bi & 15;
  const int slen = seqlen[b];

  // W1 fragments: row = l15 (hid-local within wave), k = quad*8+j.
  // Same bytes serve as the MFMA *A* operand after the operand swap.
  bf16x8 wh[8], wl8[8];
#pragma unroll
  for (int ks = 0; ks < 8; ++ks) {
    int off = (w * 16 + l15) * 256 + ks * 32 + quad * 8;
    wh[ks] = *(const bf16x8*)(w1h + off);
    wl8[ks] = *(const bf16x8*)(w1l + off);
  }
  // C[hid, n]: lane's 4 regs are hid = w*16 + quad*4 + r
  const float4 b1q = *(const float4*)(b1 + w * 16 + quad * 4);
  const float4 wlq = *(const float4*)(wlen + w * 16 + quad * 4);

  const int c4 = t & 63;   // float4 column owned (staging + pooling)
  const int r1 = w;        // owned rows: r1 and r1+8

  float m1 = -INFINITY, l1 = 0.f, m2 = -INFINITY, l2 = 0.f;
  float4 acc1 = {0.f, 0.f, 0.f, 0.f}, acc2 = {0.f, 0.f, 0.f, 0.f};

  const float4* xbase =
      (const float4*)(x + (((long)b * Ss + sc * TS) * Nn + ng * TN) * DIN);

  unsigned short* xcur = xs0;
  unsigned short* xnxt = xs1;

  // prologue: load + stage tile 0
  float4 cv1 = xbase[t];          // row r1,   cols c4*4..+3
  float4 cv2 = xbase[t + 512];    // row r1+8
  stage4(xcur + r1 * 520, c4 * 4, cv1);
  stage4(xcur + (r1 + 8) * 520, c4 * 4, cv2);
  __syncthreads();

  for (int i = 0; i < TS; ++i) {
    float4 nv1, nv2;
    const bool more = (i + 1 < TS);
    if (more) {  // prefetch next tile; latency hides under MFMA phase
      const float4* nb = xbase + (long)(i + 1) * (Nn * DIN / 4);
      nv1 = nb[t];
      nv2 = nb[t + 512];
    }

    // scores: C'[hid_local = quad*4+r, n = l15], 3-product bf16 split
    f32x4 sacc = {0.f, 0.f, 0.f, 0.f};
    const unsigned short* xr = xcur + l15 * 520;
#pragma unroll
    for (int ks = 0; ks < 8; ++ks) {
      const int k0 = ks * 32 + quad * 8;
      bf16x8 ah = *(const bf16x8*)(xr + k0);
      bf16x8 al = *(const bf16x8*)(xr + 256 + k0);
      sacc = __builtin_amdgcn_mfma_f32_16x16x32_bf16(wh[ks], ah, sacc, 0, 0, 0);
      sacc = __builtin_amdgcn_mfma_f32_16x16x32_bf16(wh[ks], al, sacc, 0, 0, 0);
      sacc = __builtin_amdgcn_mfma_f32_16x16x32_bf16(wl8[ks], ah, sacc, 0, 0, 0);
    }
    // in-lane reduce over this lane's 4 hid rows, then over quads
    float p = fmaxf(sacc[0] + b1q.x, 0.f) * wlq.x;
    p = fmaf(fmaxf(sacc[1] + b1q.y, 0.f), wlq.y, p);
    p = fmaf(fmaxf(sacc[2] + b1q.z, 0.f), wlq.z, p);
    p = fmaf(fmaxf(sacc[3] + b1q.w, 0.f), wlq.w, p);
    p += __shfl_xor(p, 16);
    p += __shfl_xor(p, 32);
    if (quad == 0) part[w * 16 + l15] = p;   // 16 lanes, 16 consecutive banks
    __syncthreads();  // bar 1: part visible

    // every wave reduces part -> raw[n = l15] (2 conflict-free b32 loads)
    float v = part[lane] + part[lane + 64];
    v += __shfl_xor(v, 16);
    v += __shfl_xor(v, 32);
    const int s = sc * TS + i;
    const float mask = (s < slen) ? 1.0f : -10.0f;
    const float s1v = __shfl(v, r1) * mask;        // wave-uniform
    const float s2v = __shfl(v, r1 + 8) * mask;    // wave-uniform

    // online softmax + pooled accumulate from registers (exact fp32)
    float mn1 = fmaxf(m1, s1v);
    if (mn1 > m1) {  // wave-uniform branch; rescale is rare
      float a = __expf(m1 - mn1);
      l1 *= a;
      acc1.x *= a; acc1.y *= a; acc1.z *= a; acc1.w *= a;
      m1 = mn1;
    }
    float e1 = __expf(s1v - m1);
    l1 += e1;
    acc1.x = fmaf(e1, cv1.x, acc1.x);
    acc1.y = fmaf(e1, cv1.y, acc1.y);
    acc1.z = fmaf(e1, cv1.z, acc1.z);
    acc1.w = fmaf(e1, cv1.w, acc1.w);

    float mn2 = fmaxf(m2, s2v);
    if (mn2 > m2) {
      float a = __expf(m2 - mn2);
      l2 *= a;
      acc2.x *= a; acc2.y *= a; acc2.z *= a; acc2.w *= a;
      m2 = mn2;
    }
    float e2 = __expf(s2v - m2);
    l2 += e2;
    acc2.x = fmaf(e2, cv2.x, acc2.x);
    acc2.y = fmaf(e2, cv2.y, acc2.y);
    acc2.z = fmaf(e2, cv2.z, acc2.z);
    acc2.w = fmaf(e2, cv2.w, acc2.w);

    if (more) {
      stage4(xnxt + r1 * 520, c4 * 4, nv1);
      stage4(xnxt + (r1 + 8) * 520, c4 * 4, nv2);
      cv1 = nv1;
      cv2 = nv2;
      unsigned short* tmp = xcur; xcur = xnxt; xnxt = tmp;
      __syncthreads();  // bar 2: staged tile ready, part safe to rewrite
    }
  }

  // write partials: wave w writes rows w and w+8 (1 KB contiguous per row)
  float* dst1 = pp + ((long)bi * TN + r1) * 256 + c4 * 4;
  *(float4*)dst1 = acc1;
  float* dst2 = pp + ((long)bi * TN + r1 + 8) * 256 + c4 * 4;
  *(float4*)dst2 = acc2;
  if (lane == 0) {
    pml[bi * 32 + r1] = m1;
    pml[bi * 32 + r1 + 8] = m2;
    pml[bi * 32 + 16 + r1] = l1;
    pml[bi * 32 + 16 + r1 + 8] = l2;
  }
}

// ---- combine partials + gated readout ----
// grid 1024 = (b,n); block 256
__global__ __launch_bounds__(256) void combine_readout(
    const float* __restrict__ pml, const float* __restrict__ pp,
    const float* __restrict__ Wa, const float* __restrict__ ba,
    const float* __restrict__ We, const float* __restrict__ be,
    const float* __restrict__ Wf, const float* __restrict__ bfv,
    float* __restrict__ g) {
  const int bi = blockIdx.x;
  const int b = bi >> 7, n = bi & 127;
  const int ng = n >> 4, nl = n & 15;
  const int t = threadIdx.x;
  __shared__ float coef[16];
  __shared__ __align__(16) float p[256];
  __shared__ __align__(16) float tv[256];

  if (t < 16) {
    const int blk = b * 128 + ng * 16 + t;   // chunk t
    float m = pml[blk * 32 + nl];
    float l = pml[blk * 32 + 16 + nl];
    float M = m;
#pragma unroll
    for (int off = 1; off < 16; off <<= 1) M = fmaxf(M, __shfl_xor(M, off));
    float z = l * expf(m - M);
    float L = z;
#pragma unroll
    for (int off = 1; off < 16; off <<= 1) L += __shfl_xor(L, off);
    coef[t] = expf(m - M) / L;
  }
  __syncthreads();

  float accd = 0.f;
#pragma unroll
  for (int c = 0; c < 16; ++c) {
    accd += coef[c] * pp[((long)(b * 128 + ng * 16 + c) * TN + nl) * 256 + t];
  }
  p[t] = accd;
  __syncthreads();

  float da = ba[t], de = be[t];
  const float4* pa = (const float4*)p;
  const float4* wa = (const float4*)(Wa + (long)t * 256);
  const float4* we = (const float4*)(We + (long)t * 256);
#pragma unroll 4
  for (int i = 0; i < 64; ++i) {
    float4 pv = pa[i], av = wa[i], ev = we[i];
    da += pv.x * av.x + pv.y * av.y + pv.z * av.z + pv.w * av.w;
    de += pv.x * ev.x + pv.y * ev.y + pv.z * ev.z + pv.w * ev.w;
  }
  float sig = 1.0f / (1.0f + expf(-da));
  float th = tanhf(de);
  tv[t] = sig * th;
  __syncthreads();
  if (t < 64) {
    float go = bfv[t];
    const float4* wf = (const float4*)(Wf + (long)t * 256);
    const float4* tp = (const float4*)tv;
#pragma unroll 4
    for (int i = 0; i < 64; ++i) {
      float4 a = tp[i], q = wf[i];
      go += a.x * q.x + a.y * q.y + a.z * q.z + a.w * q.w;
    }
    g[(long)bi * 64 + t] = go;
  }
}

// ---- finalize: out[b,:] = sum_n g / 128 + max_n g ----
__global__ __launch_bounds__(512) void finalize_kernel(const float* __restrict__ g,
                                                       float* __restrict__ out) {
  const int b = blockIdx.x;   // 8
  const int t = threadIdx.x;  // 512
  const int o = t & 63, ns = t >> 6;
  float sum = 0.f, mx = -INFINITY;
  for (int n = ns; n < Nn; n += 8) {
    float v = g[((long)b * Nn + n) * DOUT + o];
    sum += v;
    mx = fmaxf(mx, v);
  }
  __shared__ float s1[8][64], s2[8][64];
  s1[ns][o] = sum;
  s2[ns][o] = mx;
  __syncthreads();
  if (ns == 0) {
#pragma unroll
    for (int ww = 1; ww < 8; ++ww) {
      sum += s1[ww][o];
      mx = fmaxf(mx, s2[ww][o]);
    }
    out[b * 64 + o] = sum * (1.0f / 128.0f) + mx;
  }
}

extern "C" void kernel_launch(void* const* d_in, const int* in_sizes, int n_in,
                              void* d_out, int out_size, void* d_ws, size_t ws_size,
                              hipStream_t stream) {
  const float* x   = (const float*)d_in[0];
  const int* seql  = (const int*)d_in[1];
  const float* W1  = (const float*)d_in[2];
  const float* b1  = (const float*)d_in[3];
  const float* wl  = (const float*)d_in[4];
  const float* Wa  = (const float*)d_in[5];
  const float* ba  = (const float*)d_in[6];
  const float* We  = (const float*)d_in[7];
  const float* be  = (const float*)d_in[8];
  const float* Wf  = (const float*)d_in[9];
  const float* bfv = (const float*)d_in[10];
  float* out = (float*)d_out;

  char* ws = (char*)d_ws;
  unsigned short* w1h = (unsigned short*)(ws);                   // 64 KB
  unsigned short* w1l = (unsigned short*)(ws + 65536);           // 64 KB
  float* pml = (float*)(ws + 131072);                            // 128 KB (1024*32)
  float* pp  = (float*)(ws + 262144);                            // 16 MB (1024*16*256)
  float* g   = (float*)(ws + 262144 + 16777216);                 // 256 KB

  prep_w1<<<128, 256, 0, stream>>>(W1, w1h, w1l);
  flash_kernel<<<1024, 512, 0, stream>>>(x, w1h, w1l, b1, wl, seql, pml, pp);
  combine_readout<<<1024, 256, 0, stream>>>(pml, pp, Wa, ba, We, be, Wf, bfv, g);
  finalize_kernel<<<8, 512, 0, stream>>>(g, out);
}

// Round 2
// 752.974 us; speedup vs baseline: 1.1224x; 1.0477x over previous
//
#include <hip/hip_runtime.h>
#include <hip/hip_bf16.h>

#define Bb 8
#define Ss 512
#define Nn 128
#define DIN 256
#define DHID 128
#define DOUT 64
#define TN 16   // n rows per tile / block
#define TS 32   // s values per block (16 chunks)

typedef __attribute__((ext_vector_type(8))) __bf16 bf16x8;
typedef __attribute__((ext_vector_type(4))) __bf16 bf16x4;
typedef __attribute__((ext_vector_type(4))) float f32x4;

__device__ __forceinline__ unsigned short f2bf(float f) {
  unsigned u = __float_as_uint(f);
  u += 0x7fffu + ((u >> 16) & 1u);
  return (unsigned short)(u >> 16);
}
__device__ __forceinline__ float bf2f(unsigned short h) {
  return __uint_as_float(((unsigned)h) << 16);
}

// ---- prep: split W1 (128x256 fp32) into bf16 hi + lo residual ----
__global__ void prep_w1(const float* __restrict__ W1,
                        unsigned short* __restrict__ w1h,
                        unsigned short* __restrict__ w1l) {
  int i = blockIdx.x * 256 + threadIdx.x;   // grid 128 -> 32768 = exact
  float f = W1[i];
  unsigned short h = f2bf(f);
  w1h[i] = h;
  w1l[i] = f2bf(f - bf2f(h));
}

// Convert 4 floats -> bf16 hi (RNE via native casts -> v_cvt_pk_bf16_f32)
// + bf16 lo residual; store as two 8B writes into an xs row.
__device__ __forceinline__ void stage4(unsigned short* row, int ci, float4 v) {
  bf16x4 hv, lv;
  hv[0] = (__bf16)v.x; hv[1] = (__bf16)v.y;
  hv[2] = (__bf16)v.z; hv[3] = (__bf16)v.w;
  lv[0] = (__bf16)(v.x - (float)hv[0]);
  lv[1] = (__bf16)(v.y - (float)hv[1]);
  lv[2] = (__bf16)(v.z - (float)hv[2]);
  lv[3] = (__bf16)(v.w - (float)hv[3]);
  *(bf16x4*)(row + ci) = hv;
  *(bf16x4*)(row + 256 + ci) = lv;
}

// ---- fused flash kernel: scores + online softmax + weighted pooling ----
// grid 1024 = b(8) x ng(8) x sc(16); block 512 = 8 waves.
// ONE barrier per s-iter: part[] is ping-ponged (part[pb] write pre-bar,
// read post-bar; reuse separated by the next bar), and next-tile staging
// is issued pre-bar into the buffer last read pre-previous-bar.
__global__ __launch_bounds__(512, 4) void flash_kernel(
    const float* __restrict__ x, const unsigned short* __restrict__ w1h,
    const unsigned short* __restrict__ w1l, const float* __restrict__ b1,
    const float* __restrict__ wlen, const int* __restrict__ seqlen,
    float* __restrict__ pml, float* __restrict__ pp) {
  __shared__ __align__(16) unsigned short xs0[TN * 520];  // hi [0,256), lo [256,512), pad 8
  __shared__ __align__(16) unsigned short xs1[TN * 520];
  __shared__ float part[2][128];   // ping-pong [wave][n] flat

  const int t = threadIdx.x;
  const int lane = t & 63;
  const int w = t >> 6;        // wave 0..7
  const int quad = lane >> 4;  // 0..3
  const int l15 = lane & 15;

  const int bi = blockIdx.x;
  const int b = bi >> 7;
  const int ng = (bi >> 4) & 7;
  const int sc = bi & 15;
  const int slen = seqlen[b];

  // W1 fragments: row = l15 (hid-local within wave), k = quad*8+j.
  bf16x8 wh[8], wl8[8];
#pragma unroll
  for (int ks = 0; ks < 8; ++ks) {
    int off = (w * 16 + l15) * 256 + ks * 32 + quad * 8;
    wh[ks] = *(const bf16x8*)(w1h + off);
    wl8[ks] = *(const bf16x8*)(w1l + off);
  }
  // C[hid, n]: lane's 4 regs are hid = w*16 + quad*4 + r
  const float4 b1q = *(const float4*)(b1 + w * 16 + quad * 4);
  const float4 wlq = *(const float4*)(wlen + w * 16 + quad * 4);

  const int c4 = t & 63;   // float4 column owned (staging + pooling)
  const int r1 = w;        // owned rows: r1 and r1+8

  float m1 = -INFINITY, l1 = 0.f, m2 = -INFINITY, l2 = 0.f;
  float4 acc1 = {0.f, 0.f, 0.f, 0.f}, acc2 = {0.f, 0.f, 0.f, 0.f};

  const float4* xbase =
      (const float4*)(x + (((long)b * Ss + sc * TS) * Nn + ng * TN) * DIN);

  unsigned short* xcur = xs0;
  unsigned short* xnxt = xs1;

  // prologue: load + stage tile 0
  float4 cv1 = xbase[t];          // row r1,   cols c4*4..+3
  float4 cv2 = xbase[t + 512];    // row r1+8
  stage4(xcur + r1 * 520, c4 * 4, cv1);
  stage4(xcur + (r1 + 8) * 520, c4 * 4, cv2);
  __syncthreads();

  int pb = 0;
  for (int i = 0; i < TS; ++i) {
    float4 nv1, nv2;
    const bool more = (i + 1 < TS);
    if (more) {  // prefetch next tile; latency hides under MFMA phase
      const float4* nb = xbase + (long)(i + 1) * (Nn * DIN / 4);
      nv1 = nb[t];
      nv2 = nb[t + 512];
    }

    // scores: C'[hid_local = quad*4+r, n = l15], 3-product bf16 split
    f32x4 sacc = {0.f, 0.f, 0.f, 0.f};
    const unsigned short* xr = xcur + l15 * 520;
#pragma unroll
    for (int ks = 0; ks < 8; ++ks) {
      const int k0 = ks * 32 + quad * 8;
      bf16x8 ah = *(const bf16x8*)(xr + k0);
      bf16x8 al = *(const bf16x8*)(xr + 256 + k0);
      sacc = __builtin_amdgcn_mfma_f32_16x16x32_bf16(wh[ks], ah, sacc, 0, 0, 0);
      sacc = __builtin_amdgcn_mfma_f32_16x16x32_bf16(wh[ks], al, sacc, 0, 0, 0);
      sacc = __builtin_amdgcn_mfma_f32_16x16x32_bf16(wl8[ks], ah, sacc, 0, 0, 0);
    }
    // in-lane reduce over this lane's 4 hid rows, then over quads
    float p = fmaxf(sacc[0] + b1q.x, 0.f) * wlq.x;
    p = fmaf(fmaxf(sacc[1] + b1q.y, 0.f), wlq.y, p);
    p = fmaf(fmaxf(sacc[2] + b1q.z, 0.f), wlq.z, p);
    p = fmaf(fmaxf(sacc[3] + b1q.w, 0.f), wlq.w, p);
    p += __shfl_xor(p, 16);
    p += __shfl_xor(p, 32);
    if (quad == 0) part[pb][w * 16 + l15] = p;

    if (more) {  // stage next tile pre-barrier (xnxt last read pre-prev-bar)
      stage4(xnxt + r1 * 520, c4 * 4, nv1);
      stage4(xnxt + (r1 + 8) * 520, c4 * 4, nv2);
    }
    __syncthreads();  // the single barrier

    // every wave reduces part -> raw[n = l15] (2 conflict-free b32 loads)
    float v = part[pb][lane] + part[pb][lane + 64];
    v += __shfl_xor(v, 16);
    v += __shfl_xor(v, 32);
    const int s = sc * TS + i;
    const float mask = (s < slen) ? 1.0f : -10.0f;
    const float s1v = __shfl(v, r1) * mask;        // wave-uniform
    const float s2v = __shfl(v, r1 + 8) * mask;    // wave-uniform

    // online softmax + pooled accumulate from registers (exact fp32)
    float mn1 = fmaxf(m1, s1v);
    if (mn1 > m1) {  // wave-uniform branch
      float a = __expf(m1 - mn1);
      l1 *= a;
      acc1.x *= a; acc1.y *= a; acc1.z *= a; acc1.w *= a;
      m1 = mn1;
    }
    float e1 = __expf(s1v - m1);
    l1 += e1;
    acc1.x = fmaf(e1, cv1.x, acc1.x);
    acc1.y = fmaf(e1, cv1.y, acc1.y);
    acc1.z = fmaf(e1, cv1.z, acc1.z);
    acc1.w = fmaf(e1, cv1.w, acc1.w);

    float mn2 = fmaxf(m2, s2v);
    if (mn2 > m2) {
      float a = __expf(m2 - mn2);
      l2 *= a;
      acc2.x *= a; acc2.y *= a; acc2.z *= a; acc2.w *= a;
      m2 = mn2;
    }
    float e2 = __expf(s2v - m2);
    l2 += e2;
    acc2.x = fmaf(e2, cv2.x, acc2.x);
    acc2.y = fmaf(e2, cv2.y, acc2.y);
    acc2.z = fmaf(e2, cv2.z, acc2.z);
    acc2.w = fmaf(e2, cv2.w, acc2.w);

    if (more) {
      cv1 = nv1;
      cv2 = nv2;
      unsigned short* tmp = xcur; xcur = xnxt; xnxt = tmp;
    }
    pb ^= 1;
  }

  // write partials: wave w writes rows w and w+8 (1 KB contiguous per row)
  float* dst1 = pp + ((long)bi * TN + r1) * 256 + c4 * 4;
  *(float4*)dst1 = acc1;
  float* dst2 = pp + ((long)bi * TN + r1 + 8) * 256 + c4 * 4;
  *(float4*)dst2 = acc2;
  if (lane == 0) {
    pml[bi * 32 + r1] = m1;
    pml[bi * 32 + r1 + 8] = m2;
    pml[bi * 32 + 16 + r1] = l1;
    pml[bi * 32 + 16 + r1 + 8] = l2;
  }
}

// ---- combine partials + gated readout ----
// grid 256 = (b, group of 4 consecutive n); block 256.
// 4 n per block cuts Wa/We L2 streaming 4x (590 MB -> ~150 MB); weight
// rows are read once and applied to 4 pooled vectors held in LDS.
__global__ __launch_bounds__(256) void combine_readout(
    const float* __restrict__ pml, const float* __restrict__ pp,
    const float* __restrict__ Wa, const float* __restrict__ ba,
    const float* __restrict__ We, const float* __restrict__ be,
    const float* __restrict__ Wf, const float* __restrict__ bfv,
    float* __restrict__ g) {
  const int bi = blockIdx.x;
  const int b = bi >> 5;          // 0..7
  const int n0 = (bi & 31) * 4;   // 0..124, 4 consecutive n share ng
  const int ng = n0 >> 4;
  const int nl0 = n0 & 15;
  const int t = threadIdx.x;
  __shared__ float coef[4][16];
  __shared__ __align__(16) float p4[4][256];
  __shared__ __align__(16) float tv4[4][256];

  if (t < 64) {   // wave 0: j = t>>4 (node), c = t&15 (chunk)
    const int j = t >> 4, c = t & 15;
    const int blk = b * 128 + ng * 16 + c;
    float m = pml[blk * 32 + nl0 + j];
    float l = pml[blk * 32 + 16 + nl0 + j];
    float M = m;
#pragma unroll
    for (int off = 1; off < 16; off <<= 1) M = fmaxf(M, __shfl_xor(M, off));
    float z = l * expf(m - M);
    float L = z;
#pragma unroll
    for (int off = 1; off < 16; off <<= 1) L += __shfl_xor(L, off);
    coef[j][c] = expf(m - M) / L;
  }
  __syncthreads();

  // combine 16 chunk-partials for the 4 nodes (coalesced 1KB rows)
  float a0 = 0.f, a1 = 0.f, a2 = 0.f, a3 = 0.f;
#pragma unroll 4
  for (int c = 0; c < 16; ++c) {
    const float* base = pp + ((long)(b * 128 + ng * 16 + c) * TN + nl0) * 256;
    a0 += coef[0][c] * base[t];
    a1 += coef[1][c] * base[256 + t];
    a2 += coef[2][c] * base[512 + t];
    a3 += coef[3][c] * base[768 + t];
  }
  p4[0][t] = a0; p4[1][t] = a1; p4[2][t] = a2; p4[3][t] = a3;
  __syncthreads();

  // gated readout: thread t = output col; weight row read once for 4 nodes
  const float bat = ba[t], bet = be[t];
  float da0 = 0.f, da1 = 0.f, da2 = 0.f, da3 = 0.f;
  float de0 = 0.f, de1 = 0.f, de2 = 0.f, de3 = 0.f;
  const float4* wa = (const float4*)(Wa + (long)t * 256);
  const float4* we = (const float4*)(We + (long)t * 256);
  const float4* q0 = (const float4*)p4[0];
  const float4* q1 = (const float4*)p4[1];
  const float4* q2 = (const float4*)p4[2];
  const float4* q3 = (const float4*)p4[3];
#pragma unroll 2
  for (int i = 0; i < 64; ++i) {
    float4 av = wa[i], ev = we[i];
    float4 v0 = q0[i], v1 = q1[i], v2 = q2[i], v3 = q3[i];
    da0 += v0.x * av.x + v0.y * av.y + v0.z * av.z + v0.w * av.w;
    de0 += v0.x * ev.x + v0.y * ev.y + v0.z * ev.z + v0.w * ev.w;
    da1 += v1.x * av.x + v1.y * av.y + v1.z * av.z + v1.w * av.w;
    de1 += v1.x * ev.x + v1.y * ev.y + v1.z * ev.z + v1.w * ev.w;
    da2 += v2.x * av.x + v2.y * av.y + v2.z * av.z + v2.w * av.w;
    de2 += v2.x * ev.x + v2.y * ev.y + v2.z * ev.z + v2.w * ev.w;
    da3 += v3.x * av.x + v3.y * av.y + v3.z * av.z + v3.w * av.w;
    de3 += v3.x * ev.x + v3.y * ev.y + v3.z * ev.z + v3.w * ev.w;
  }
  tv4[0][t] = (1.0f / (1.0f + expf(-(bat + da0)))) * tanhf(bet + de0);
  tv4[1][t] = (1.0f / (1.0f + expf(-(bat + da1)))) * tanhf(bet + de1);
  tv4[2][t] = (1.0f / (1.0f + expf(-(bat + da2)))) * tanhf(bet + de2);
  tv4[3][t] = (1.0f / (1.0f + expf(-(bat + da3)))) * tanhf(bet + de3);
  __syncthreads();

  // fc2: 4 waves, wave j handles node n0+j, lane o = out col
  {
    const int j = t >> 6, o = t & 63;
    float go = bfv[o];
    const float4* wf = (const float4*)(Wf + (long)o * 256);
    const float4* tp = (const float4*)tv4[j];
#pragma unroll 4
    for (int i = 0; i < 64; ++i) {
      float4 a = tp[i], q = wf[i];
      go += a.x * q.x + a.y * q.y + a.z * q.z + a.w * q.w;
    }
    g[(long)(b * 128 + n0 + j) * 64 + o] = go;
  }
}

// ---- finalize: out[b,:] = sum_n g / 128 + max_n g ----
__global__ __launch_bounds__(512) void finalize_kernel(const float* __restrict__ g,
                                                       float* __restrict__ out) {
  const int b = blockIdx.x;   // 8
  const int t = threadIdx.x;  // 512
  const int o = t & 63, ns = t >> 6;
  float sum = 0.f, mx = -INFINITY;
  for (int n = ns; n < Nn; n += 8) {
    float v = g[((long)b * Nn + n) * DOUT + o];
    sum += v;
    mx = fmaxf(mx, v);
  }
  __shared__ float s1[8][64], s2[8][64];
  s1[ns][o] = sum;
  s2[ns][o] = mx;
  __syncthreads();
  if (ns == 0) {
#pragma unroll
    for (int ww = 1; ww < 8; ++ww) {
      sum += s1[ww][o];
      mx = fmaxf(mx, s2[ww][o]);
    }
    out[b * 64 + o] = sum * (1.0f / 128.0f) + mx;
  }
}

extern "C" void kernel_launch(void* const* d_in, const int* in_sizes, int n_in,
                              void* d_out, int out_size, void* d_ws, size_t ws_size,
                              hipStream_t stream) {
  const float* x   = (const float*)d_in[0];
  const int* seql  = (const int*)d_in[1];
  const float* W1  = (const float*)d_in[2];
  const float* b1  = (const float*)d_in[3];
  const float* wl  = (const float*)d_in[4];
  const float* Wa  = (const float*)d_in[5];
  const float* ba  = (const float*)d_in[6];
  const float* We  = (const float*)d_in[7];
  const float* be  = (const float*)d_in[8];
  const float* Wf  = (const float*)d_in[9];
  const float* bfv = (const float*)d_in[10];
  float* out = (float*)d_out;

  char* ws = (char*)d_ws;
  unsigned short* w1h = (unsigned short*)(ws);                   // 64 KB
  unsigned short* w1l = (unsigned short*)(ws + 65536);           // 64 KB
  float* pml = (float*)(ws + 131072);                            // 128 KB (1024*32)
  float* pp  = (float*)(ws + 262144);                            // 16 MB (1024*16*256)
  float* g   = (float*)(ws + 262144 + 16777216);                 // 256 KB

  prep_w1<<<128, 256, 0, stream>>>(W1, w1h, w1l);
  flash_kernel<<<1024, 512, 0, stream>>>(x, w1h, w1l, b1, wl, seql, pml, pp);
  combine_readout<<<256, 256, 0, stream>>>(pml, pp, Wa, ba, We, be, Wf, bfv, g);
  finalize_kernel<<<8, 512, 0, stream>>>(g, out);
}